// Round 22
// baseline (264.249 us; speedup 1.0000x reference)
//
#include <hip/hip_runtime.h>
#include <hip/hip_bf16.h>

#define HW 16384
#define NC 256
#define NO 64
#define NPM 1048576          // floats per (b, modality)
#define EPS_IN 1e-5f
#define DBLK 1024            // k_dots blocks.x
#define WIN 1024             // floats per modality per window
#define SPX 256              // pixels per k_gemm block window (R11 geometry)
#define SCH 32               // channels per staged chunk
#define NCHK 8               // 256 / SCH
#define PAD 4                // floats of row padding in LDS

typedef float f32x4 __attribute__((ext_vector_type(4)));
typedef short bhalf8 __attribute__((ext_vector_type(8)));

static __device__ __forceinline__ short f2bf(float f){
  __bf16 h = (__bf16)f;
  return __builtin_bit_cast(short, h);
}

// ws float layout: [256,320) probs[b][m] ; [320,2368) stats[(b*64+o)*2+{s,q}] ;
//                  [8192, +16*DBLK*10) partials (probe scratch after k_attn)

__global__ void k_zero(float* ws){
  int i = blockIdx.x*256 + threadIdx.x;
  if (i < 2048) ws[320 + i] = 0.f;   // stats only
}

// Pass 1: Gram partials (proven ~50us / 5.4TB/s structure, untouched).
__global__ void k_dots(const float* __restrict__ x, float* __restrict__ partials){
  __shared__ float lds[4][WIN];
  __shared__ float red[4][16];
  const int b = blockIdx.y, bx = blockIdx.x;
  const int tid = threadIdx.x;
  const int w = tid >> 6, lane = tid & 63;
  const int wi = (bx + b*67) & (DBLK-1);
  const float* src = x + (size_t)b*4*NPM + (size_t)w*NPM + (size_t)wi*WIN + lane*4;

  #pragma unroll
  for (int li=0; li<4; li++){
    __builtin_amdgcn_global_load_lds(
        (const __attribute__((address_space(1))) void*)(src + li*256),
        (__attribute__((address_space(3))) void*)&lds[w][li*256],
        16, 0, 0);
  }
  __syncthreads();

  float4 vv[4];
  #pragma unroll
  for (int m=0;m<4;m++) vv[m] = *(const float4*)&lds[m][tid*4];
  float acc[10];
  int k=0;
  #pragma unroll
  for (int i=0;i<4;i++)
    #pragma unroll
    for (int j=i;j<4;j++,k++)
      acc[k] = vv[i].x*vv[j].x + vv[i].y*vv[j].y + vv[i].z*vv[j].z + vv[i].w*vv[j].w;

  #pragma unroll
  for (int kk=0;kk<10;kk++){
    float s = acc[kk];
    #pragma unroll
    for (int off=1; off<64; off<<=1) s += __shfl_xor(s, off, 64);
    acc[kk]=s;
  }
  if (lane==0){
    #pragma unroll
    for (int kk=0;kk<10;kk++) red[w][kk] = acc[kk];
  }
  __syncthreads();
  if (tid<10){
    float s = red[0][tid] + red[1][tid] + red[2][tid] + red[3][tid];
    partials[((size_t)b*DBLK + bx)*10 + tid] = s;
  }
}

__global__ void k_attn(const float* __restrict__ partials, float* __restrict__ probs){
  __shared__ float red[4][16];
  int b = blockIdx.x, tid = threadIdx.x;       // 256 threads
  int w = tid>>6, lane = tid&63;
  float a[10];
  #pragma unroll
  for (int kk=0;kk<10;kk++) a[kk]=0.f;
  #pragma unroll
  for (int r=0;r<DBLK/256;r++){
    const float* p = partials + ((size_t)b*DBLK + r*256 + tid)*10;
    #pragma unroll
    for (int kk=0;kk<10;kk++) a[kk]+=p[kk];
  }
  #pragma unroll
  for (int kk=0;kk<10;kk++){
    float s=a[kk];
    #pragma unroll
    for (int off=1;off<64;off<<=1) s+=__shfl_xor(s,off,64);
    a[kk]=s;
  }
  if (lane==0){
    #pragma unroll
    for (int kk=0;kk<10;kk++) red[w][kk]=a[kk];
  }
  __syncthreads();
  if (tid==0){
    float d[10];
    #pragma unroll
    for (int kk=0;kk<10;kk++) d[kk]=red[0][kk]+red[1][kk]+red[2][kk]+red[3][kk];
    float D[4][4];
    int k2=0;
    #pragma unroll
    for (int i=0;i<4;i++)
      #pragma unroll
      for (int j=i;j<4;j++,k2++){ D[i][j]=d[k2]; D[j][i]=d[k2]; }
    float nrm[4];
    #pragma unroll
    for (int m=0;m<4;m++) nrm[m]=fmaxf(sqrtf(D[m][m]),1e-8f);
    float sc[4];
    #pragma unroll
    for (int i=0;i<4;i++){
      float s=0.f;
      #pragma unroll
      for (int j=0;j<4;j++) s += D[i][j]/(nrm[i]*nrm[j]);
      sc[i] = -(s-1.0f);
    }
    float mx = fmaxf(fmaxf(sc[0],sc[1]), fmaxf(sc[2],sc[3]));
    float e[4], se=0.f;
    #pragma unroll
    for (int m=0;m<4;m++){ e[m]=expf(sc[m]-mx); se+=e[m]; }
    #pragma unroll
    for (int m=0;m<4;m++) probs[b*4+m]=e[m]/se;
  }
}

// PROBE 1: stage-only — R11's exact staging/barrier skeleton, NO LDS reads,
// NO MFMA, NO y-writes. Isolates the x-read path cost.
__launch_bounds__(256, 2)
__global__ void k_probe_stage(const float* __restrict__ x, float* __restrict__ scr){
  __shared__ float buf[2][SCH][SPX+PAD];
  const int b  = blockIdx.y;
  const int pw = blockIdx.x * SPX;
  const int tid = threadIdx.x;
  const int wid = tid >> 6, lane = tid & 63;
  const float* xb = x + (size_t)b*NC*HW + pw;

  auto STAGE = [&](int cc, int cur){
    #pragma unroll
    for (int j=0; j<8; j++){
      int ch_l = wid*8 + j;
      __builtin_amdgcn_global_load_lds(
          (const __attribute__((address_space(1))) void*)(xb + (size_t)(cc*SCH + ch_l)*HW + lane*4),
          (__attribute__((address_space(3))) void*)&buf[cur][ch_l][0],
          16, 0, 0);
    }
  };

  STAGE(0, 0);
  int cur = 0;
  #pragma unroll 1
  for (int cc=0; cc<NCHK; cc++){
    if (cc < NCHK-1){
      STAGE(cc+1, cur^1);
      asm volatile("s_waitcnt vmcnt(8)" ::: "memory");
    } else {
      asm volatile("s_waitcnt vmcnt(0)" ::: "memory");
    }
    __builtin_amdgcn_s_barrier();
    __builtin_amdgcn_sched_barrier(0);
    __builtin_amdgcn_sched_barrier(0);
    __builtin_amdgcn_s_barrier();
    cur ^= 1;
  }
  if (lane == 0)
    scr[((size_t)b*gridDim.x + blockIdx.x)*4 + wid] = buf[0][wid*8][1];
}

// PROBE 2: write-only — the EXACT y-store address pattern of the real
// epilogue, no x reads, no LDS, no stats. Real k_gemm overwrites y after.
__launch_bounds__(256, 2)
__global__ void k_probe_write(const float* __restrict__ ws, float* __restrict__ y){
  const int b   = blockIdx.y;
  const int pw  = blockIdx.x * SPX;
  const int tid = threadIdx.x;
  const int wid = tid >> 6;
  const int lane = tid & 63;
  const int l15 = lane & 15;
  const int lg  = lane >> 4;
  const int wr  = wid & 1;
  const int wp  = wid >> 1;
  float v0 = ws[256 + b*4];

  #pragma unroll
  for (int rt=0; rt<2; rt++){
    #pragma unroll
    for (int pt=0; pt<8; pt++){
      size_t ybase = ((size_t)(b*NO + wr*32 + rt*16 + lg*4))*HW + pw + wp*128 + pt*16 + l15;
      #pragma unroll
      for (int r=0; r<4; r++)
        y[ybase + (size_t)r*HW] = v0 + rt + pt + r;
    }
  }
}

// REAL GEMM: R11's exact kernel (best measured, ~130us in 213.6 total).
__launch_bounds__(256, 2)
__global__ void k_gemm(const float* __restrict__ x, const float* __restrict__ w,
                       const float* __restrict__ ws, float* __restrict__ y,
                       float* __restrict__ stats){
  __shared__ float buf[2][SCH][SPX+PAD];
  const int b   = blockIdx.y;
  const int pw  = blockIdx.x * SPX;
  const int tid = threadIdx.x;
  const int wid = tid >> 6;
  const int lane = tid & 63;
  const int l15 = lane & 15;
  const int lg  = lane >> 4;
  const int wr  = wid & 1;      // row half   (32 rows)
  const int wp  = wid >> 1;     // pixel half (128 px)

  const float* probs = ws + 256 + b*4;
  float pm[4] = {probs[0], probs[1], probs[2], probs[3]};
  bhalf8 afrag[2][NCHK];
  const float4* w4 = reinterpret_cast<const float4*>(w);
  #pragma unroll
  for (int rt=0; rt<2; rt++){
    int row = wr*32 + rt*16 + l15;
    #pragma unroll
    for (int ks=0; ks<NCHK; ks++){
      float s = pm[ks>>1];
      float4 a0 = w4[row*64 + ks*8 + lg];
      float4 a1 = w4[row*64 + ks*8 + lg + 4];
      bhalf8 f;
      f[0]=f2bf(a0.x*s); f[1]=f2bf(a0.y*s); f[2]=f2bf(a0.z*s); f[3]=f2bf(a0.w*s);
      f[4]=f2bf(a1.x*s); f[5]=f2bf(a1.y*s); f[6]=f2bf(a1.z*s); f[7]=f2bf(a1.w*s);
      afrag[rt][ks] = f;
    }
  }

  const float* xb = x + (size_t)b*NC*HW + pw;

  auto STAGE = [&](int cc, int cur){
    #pragma unroll
    for (int j=0; j<8; j++){
      int ch_l = wid*8 + j;
      __builtin_amdgcn_global_load_lds(
          (const __attribute__((address_space(1))) void*)(xb + (size_t)(cc*SCH + ch_l)*HW + lane*4),
          (__attribute__((address_space(3))) void*)&buf[cur][ch_l][0],
          16, 0, 0);
    }
  };

  f32x4 acc[2][8];
  #pragma unroll
  for (int rt=0; rt<2; rt++)
    #pragma unroll
    for (int pt=0; pt<8; pt++) acc[rt][pt] = (f32x4){0.f,0.f,0.f,0.f};

  STAGE(0, 0);
  int cur = 0;
  #pragma unroll 1
  for (int cc=0; cc<NCHK; cc++){
    if (cc < NCHK-1){
      STAGE(cc+1, cur^1);
      asm volatile("s_waitcnt vmcnt(8)" ::: "memory");
    } else {
      asm volatile("s_waitcnt vmcnt(0)" ::: "memory");
    }
    __builtin_amdgcn_s_barrier();
    __builtin_amdgcn_sched_barrier(0);

    const float (*bp)[SPX+PAD] = buf[cur];
    #pragma unroll
    for (int pt=0; pt<8; pt++){
      int px_l = wp*128 + pt*16 + l15;
      bhalf8 bfr;
      #pragma unroll
      for (int eh=0; eh<2; eh++)
        #pragma unroll
        for (int el=0; el<4; el++){
          int c_l = lg*4 + el + eh*16;
          bfr[eh*4+el] = f2bf(bp[c_l][px_l]);
        }
      #pragma unroll
      for (int rt=0; rt<2; rt++)
        acc[rt][pt] = __builtin_amdgcn_mfma_f32_16x16x32_bf16(afrag[rt][cc], bfr, acc[rt][pt], 0, 0, 0);
    }

    __builtin_amdgcn_sched_barrier(0);
    __builtin_amdgcn_s_barrier();
    cur ^= 1;
  }

  float sacc[2][4] = {{0}}, qacc[2][4] = {{0}};
  #pragma unroll
  for (int rt=0; rt<2; rt++){
    #pragma unroll
    for (int pt=0; pt<8; pt++){
      size_t ybase = ((size_t)(b*NO + wr*32 + rt*16 + lg*4))*HW + pw + wp*128 + pt*16 + l15;
      #pragma unroll
      for (int r=0; r<4; r++){
        float v = acc[rt][pt][r];
        y[ybase + (size_t)r*HW] = v;
        sacc[rt][r] += v;
        qacc[rt][r] += v*v;
      }
    }
  }
  #pragma unroll
  for (int rt=0; rt<2; rt++){
    #pragma unroll
    for (int r=0; r<4; r++){
      float s = sacc[rt][r], q = qacc[rt][r];
      #pragma unroll
      for (int off=1; off<16; off<<=1){
        s += __shfl_xor(s, off, 64);
        q += __shfl_xor(q, off, 64);
      }
      if (l15 == 0){
        int o = wr*32 + rt*16 + lg*4 + r;
        atomicAdd(&stats[b*128 + o*2],     s);
        atomicAdd(&stats[b*128 + o*2 + 1], q);
      }
    }
  }
}

__global__ void k_norm(float* __restrict__ y, const float* __restrict__ stats){
  int bo = blockIdx.x;
  float s = stats[bo*2], q = stats[bo*2+1];
  float mean = s * (1.f/HW);
  float var  = q * (1.f/HW) - mean*mean;
  float inv  = rsqrtf(var + EPS_IN);
  float4* yp = reinterpret_cast<float4*>(y) + (size_t)bo*(HW/4);
  #pragma unroll 4
  for (int i = threadIdx.x; i < HW/4; i += 256){
    float4 v = yp[i];
    v.x = fmaxf((v.x-mean)*inv, 0.f);
    v.y = fmaxf((v.y-mean)*inv, 0.f);
    v.z = fmaxf((v.z-mean)*inv, 0.f);
    v.w = fmaxf((v.w-mean)*inv, 0.f);
    yp[i] = v;
  }
}

extern "C" void kernel_launch(void* const* d_in, const int* in_sizes, int n_in,
                              void* d_out, int out_size, void* d_ws, size_t ws_size,
                              hipStream_t stream){
  const float* x = (const float*)d_in[0];
  const float* w = (const float*)d_in[1];
  float* out = (float*)d_out;
  float* ws  = (float*)d_ws;
  float* partials = ws + 8192;
  float* probs    = ws + 256;
  float* stats    = ws + 320;

  k_zero<<<dim3(8),          dim3(256), 0, stream>>>(ws);
  k_dots<<<dim3(DBLK,16),    dim3(256), 0, stream>>>(x, partials);
  k_attn<<<dim3(16),         dim3(256), 0, stream>>>(partials, probs);
  // probes (diagnostic; y junk from probe_write is overwritten by k_gemm)
  k_probe_stage<<<dim3(HW/SPX,16), dim3(256), 0, stream>>>(x, partials);
  k_probe_write<<<dim3(HW/SPX,16), dim3(256), 0, stream>>>(ws, out);
  k_gemm<<<dim3(HW/SPX,16),  dim3(256), 0, stream>>>(x, w, ws, out, stats);
  k_norm<<<dim3(1024),       dim3(256), 0, stream>>>(out, stats);
}

// Round 23
// 214.331 us; speedup vs baseline: 1.2329x; 1.2329x over previous
//
#include <hip/hip_runtime.h>
#include <hip/hip_bf16.h>

#define HW 16384
#define NC 256
#define NO 64
#define NPM 1048576          // floats per (b, modality)
#define EPS_IN 1e-5f
#define DBLK 1024            // k_dots blocks.x
#define WIN 1024             // floats per modality per window
#define SPX 256              // pixels per k_gemm block window (R11 geometry)
#define SCH 32               // channels per staged chunk
#define NCHK 8               // 256 / SCH
#define PAD 4                // floats of row padding in LDS

typedef float f32x4 __attribute__((ext_vector_type(4)));
typedef short bhalf8 __attribute__((ext_vector_type(8)));

static __device__ __forceinline__ short f2bf(float f){
  __bf16 h = (__bf16)f;
  return __builtin_bit_cast(short, h);
}

// ws float layout: [256,320) probs[b][m] ; [320,2368) stats[(b*64+o)*2+{s,q}] ;
//                  [8192, +16*DBLK*10) block partials

__global__ void k_zero(float* ws){
  int i = blockIdx.x*256 + threadIdx.x;
  if (i < 2048) ws[320 + i] = 0.f;   // stats only
}

// Pass 1: Gram partials (proven ~50us / 5.4TB/s structure, untouched).
__global__ void k_dots(const float* __restrict__ x, float* __restrict__ partials){
  __shared__ float lds[4][WIN];
  __shared__ float red[4][16];
  const int b = blockIdx.y, bx = blockIdx.x;
  const int tid = threadIdx.x;
  const int w = tid >> 6, lane = tid & 63;
  const int wi = (bx + b*67) & (DBLK-1);
  const float* src = x + (size_t)b*4*NPM + (size_t)w*NPM + (size_t)wi*WIN + lane*4;

  #pragma unroll
  for (int li=0; li<4; li++){
    __builtin_amdgcn_global_load_lds(
        (const __attribute__((address_space(1))) void*)(src + li*256),
        (__attribute__((address_space(3))) void*)&lds[w][li*256],
        16, 0, 0);
  }
  __syncthreads();

  float4 vv[4];
  #pragma unroll
  for (int m=0;m<4;m++) vv[m] = *(const float4*)&lds[m][tid*4];
  float acc[10];
  int k=0;
  #pragma unroll
  for (int i=0;i<4;i++)
    #pragma unroll
    for (int j=i;j<4;j++,k++)
      acc[k] = vv[i].x*vv[j].x + vv[i].y*vv[j].y + vv[i].z*vv[j].z + vv[i].w*vv[j].w;

  #pragma unroll
  for (int kk=0;kk<10;kk++){
    float s = acc[kk];
    #pragma unroll
    for (int off=1; off<64; off<<=1) s += __shfl_xor(s, off, 64);
    acc[kk]=s;
  }
  if (lane==0){
    #pragma unroll
    for (int kk=0;kk<10;kk++) red[w][kk] = acc[kk];
  }
  __syncthreads();
  if (tid<10){
    float s = red[0][tid] + red[1][tid] + red[2][tid] + red[3][tid];
    partials[((size_t)b*DBLK + bx)*10 + tid] = s;
  }
}

__global__ void k_attn(const float* __restrict__ partials, float* __restrict__ probs){
  __shared__ float red[4][16];
  int b = blockIdx.x, tid = threadIdx.x;       // 256 threads
  int w = tid>>6, lane = tid&63;
  float a[10];
  #pragma unroll
  for (int kk=0;kk<10;kk++) a[kk]=0.f;
  #pragma unroll
  for (int r=0;r<DBLK/256;r++){
    const float* p = partials + ((size_t)b*DBLK + r*256 + tid)*10;
    #pragma unroll
    for (int kk=0;kk<10;kk++) a[kk]+=p[kk];
  }
  #pragma unroll
  for (int kk=0;kk<10;kk++){
    float s=a[kk];
    #pragma unroll
    for (int off=1;off<64;off<<=1) s+=__shfl_xor(s,off,64);
    a[kk]=s;
  }
  if (lane==0){
    #pragma unroll
    for (int kk=0;kk<10;kk++) red[w][kk]=a[kk];
  }
  __syncthreads();
  if (tid==0){
    float d[10];
    #pragma unroll
    for (int kk=0;kk<10;kk++) d[kk]=red[0][kk]+red[1][kk]+red[2][kk]+red[3][kk];
    float D[4][4];
    int k2=0;
    #pragma unroll
    for (int i=0;i<4;i++)
      #pragma unroll
      for (int j=i;j<4;j++,k2++){ D[i][j]=d[k2]; D[j][i]=d[k2]; }
    float nrm[4];
    #pragma unroll
    for (int m=0;m<4;m++) nrm[m]=fmaxf(sqrtf(D[m][m]),1e-8f);
    float sc[4];
    #pragma unroll
    for (int i=0;i<4;i++){
      float s=0.f;
      #pragma unroll
      for (int j=0;j<4;j++) s += D[i][j]/(nrm[i]*nrm[j]);
      sc[i] = -(s-1.0f);
    }
    float mx = fmaxf(fmaxf(sc[0],sc[1]), fmaxf(sc[2],sc[3]));
    float e[4], se=0.f;
    #pragma unroll
    for (int m=0;m<4;m++){ e[m]=expf(sc[m]-mx); se+=e[m]; }
    #pragma unroll
    for (int m=0;m<4;m++) probs[b*4+m]=e[m]/se;
  }
}

// GEMM: R11 skeleton; compute-phase LDS reads are inline-asm ds_read_b32
// (invisible to alias analysis -> no compiler-inserted vmcnt(0) drain of the
// chunk-(cc+1) prefetch). Counted lgkmcnt(8) pipelines reads across pt;
// sched_barrier(0) fences per rule #18.
__launch_bounds__(256, 2)
__global__ void k_gemm(const float* __restrict__ x, const float* __restrict__ w,
                       const float* __restrict__ ws, float* __restrict__ y,
                       float* __restrict__ stats){
  __shared__ float buf[2][SCH][SPX+PAD];
  const int b   = blockIdx.y;
  const int pw  = blockIdx.x * SPX;
  const int tid = threadIdx.x;
  const int wid = tid >> 6;
  const int lane = tid & 63;
  const int l15 = lane & 15;
  const int lg  = lane >> 4;
  const int wr  = wid & 1;      // row half   (32 rows)
  const int wp  = wid >> 1;     // pixel half (128 px)

  const float* probs = ws + 256 + b*4;
  float pm[4] = {probs[0], probs[1], probs[2], probs[3]};
  bhalf8 afrag[2][NCHK];
  const float4* w4 = reinterpret_cast<const float4*>(w);
  #pragma unroll
  for (int rt=0; rt<2; rt++){
    int row = wr*32 + rt*16 + l15;
    #pragma unroll
    for (int ks=0; ks<NCHK; ks++){
      float s = pm[ks>>1];
      float4 a0 = w4[row*64 + ks*8 + lg];
      float4 a1 = w4[row*64 + ks*8 + lg + 4];
      bhalf8 f;
      f[0]=f2bf(a0.x*s); f[1]=f2bf(a0.y*s); f[2]=f2bf(a0.z*s); f[3]=f2bf(a0.w*s);
      f[4]=f2bf(a1.x*s); f[5]=f2bf(a1.y*s); f[6]=f2bf(a1.z*s); f[7]=f2bf(a1.w*s);
      afrag[rt][ks] = f;
    }
  }

  const float* xb = x + (size_t)b*NC*HW + pw;

  auto STAGE = [&](int cc, int cur){
    #pragma unroll
    for (int j=0; j<8; j++){
      int ch_l = wid*8 + j;
      __builtin_amdgcn_global_load_lds(
          (const __attribute__((address_space(1))) void*)(xb + (size_t)(cc*SCH + ch_l)*HW + lane*4),
          (__attribute__((address_space(3))) void*)&buf[cur][ch_l][0],
          16, 0, 0);
    }
  };

  f32x4 acc[2][8];
  #pragma unroll
  for (int rt=0; rt<2; rt++)
    #pragma unroll
    for (int pt=0; pt<8; pt++) acc[rt][pt] = (f32x4){0.f,0.f,0.f,0.f};

  STAGE(0, 0);
  int cur = 0;
  #pragma unroll 1
  for (int cc=0; cc<NCHK; cc++){
    if (cc < NCHK-1){
      STAGE(cc+1, cur^1);
      asm volatile("s_waitcnt vmcnt(8)" ::: "memory");
    } else {
      asm volatile("s_waitcnt vmcnt(0)" ::: "memory");
    }
    __builtin_amdgcn_s_barrier();        // all waves' chunk-cc writes done
    __builtin_amdgcn_sched_barrier(0);

    // compute(cc): asm ds_read pipeline. buf base = LDS offset 0 (only shared var).
    const uint32_t base = (uint32_t)(cur*SCH*(SPX+PAD)) * 4u;
    const int px_base = wp*128 + l15;
    float va[8], vb[8];
    #pragma unroll
    for (int e=0; e<8; e++){
      int c_l = lg*4 + (e&3) + (e>>2)*16;
      uint32_t off = base + (uint32_t)(c_l*(SPX+PAD) + px_base) * 4u;
      asm volatile("ds_read_b32 %0, %1" : "=v"(va[e]) : "v"(off));
    }
    #pragma unroll
    for (int pt=0; pt<8; pt++){
      float* vn = (pt&1) ? va : vb;
      if (pt < 7){
        #pragma unroll
        for (int e=0; e<8; e++){
          int c_l = lg*4 + (e&3) + (e>>2)*16;
          uint32_t off = base + (uint32_t)(c_l*(SPX+PAD) + px_base + (pt+1)*16) * 4u;
          asm volatile("ds_read_b32 %0, %1" : "=v"(vn[e]) : "v"(off));
        }
        asm volatile("s_waitcnt lgkmcnt(8)" ::: "memory");
      } else {
        asm volatile("s_waitcnt lgkmcnt(0)" ::: "memory");
      }
      __builtin_amdgcn_sched_barrier(0);   // no hoisting of consumers (rule #18)
      const float* vc = (pt&1) ? vb : va;
      bhalf8 bfr;
      #pragma unroll
      for (int e=0; e<8; e++) bfr[e] = f2bf(vc[e]);
      #pragma unroll
      for (int rt=0; rt<2; rt++)
        acc[rt][pt] = __builtin_amdgcn_mfma_f32_16x16x32_bf16(afrag[rt][cc], bfr, acc[rt][pt], 0, 0, 0);
    }

    __builtin_amdgcn_sched_barrier(0);
    __builtin_amdgcn_s_barrier();        // reads done -> buf[cur] reusable
    cur ^= 1;
  }

  // epilogue: y write + stats (C/D: row = lg*4 + r, col = l15)
  float sacc[2][4] = {{0}}, qacc[2][4] = {{0}};
  #pragma unroll
  for (int rt=0; rt<2; rt++){
    #pragma unroll
    for (int pt=0; pt<8; pt++){
      size_t ybase = ((size_t)(b*NO + wr*32 + rt*16 + lg*4))*HW + pw + wp*128 + pt*16 + l15;
      #pragma unroll
      for (int r=0; r<4; r++){
        float v = acc[rt][pt][r];
        y[ybase + (size_t)r*HW] = v;
        sacc[rt][r] += v;
        qacc[rt][r] += v*v;
      }
    }
  }
  #pragma unroll
  for (int rt=0; rt<2; rt++){
    #pragma unroll
    for (int r=0; r<4; r++){
      float s = sacc[rt][r], q = qacc[rt][r];
      #pragma unroll
      for (int off=1; off<16; off<<=1){
        s += __shfl_xor(s, off, 64);
        q += __shfl_xor(q, off, 64);
      }
      if (l15 == 0){
        int o = wr*32 + rt*16 + lg*4 + r;
        atomicAdd(&stats[b*128 + o*2],     s);
        atomicAdd(&stats[b*128 + o*2 + 1], q);
      }
    }
  }
}

__global__ void k_norm(float* __restrict__ y, const float* __restrict__ stats){
  int bo = blockIdx.x;
  float s = stats[bo*2], q = stats[bo*2+1];
  float mean = s * (1.f/HW);
  float var  = q * (1.f/HW) - mean*mean;
  float inv  = rsqrtf(var + EPS_IN);
  float4* yp = reinterpret_cast<float4*>(y) + (size_t)bo*(HW/4);
  #pragma unroll 4
  for (int i = threadIdx.x; i < HW/4; i += 256){
    float4 v = yp[i];
    v.x = fmaxf((v.x-mean)*inv, 0.f);
    v.y = fmaxf((v.y-mean)*inv, 0.f);
    v.z = fmaxf((v.z-mean)*inv, 0.f);
    v.w = fmaxf((v.w-mean)*inv, 0.f);
    yp[i] = v;
  }
}

extern "C" void kernel_launch(void* const* d_in, const int* in_sizes, int n_in,
                              void* d_out, int out_size, void* d_ws, size_t ws_size,
                              hipStream_t stream){
  const float* x = (const float*)d_in[0];
  const float* w = (const float*)d_in[1];
  float* out = (float*)d_out;
  float* ws  = (float*)d_ws;
  float* partials = ws + 8192;
  float* probs    = ws + 256;
  float* stats    = ws + 320;

  k_zero<<<dim3(8),          dim3(256), 0, stream>>>(ws);
  k_dots<<<dim3(DBLK,16),    dim3(256), 0, stream>>>(x, partials);
  k_attn<<<dim3(16),         dim3(256), 0, stream>>>(partials, probs);
  k_gemm<<<dim3(HW/SPX,16),  dim3(256), 0, stream>>>(x, w, ws, out, stats);
  k_norm<<<dim3(1024),       dim3(256), 0, stream>>>(out, stats);
}

// Round 24
// 213.542 us; speedup vs baseline: 1.2375x; 1.0037x over previous
//
#include <hip/hip_runtime.h>
#include <hip/hip_bf16.h>

#define HW 16384
#define NC 256
#define NO 64
#define NPM 1048576          // floats per (b, modality)
#define EPS_IN 1e-5f
#define DBLK 1024            // k_dots blocks.x
#define WIN 1024             // floats per modality per window
#define SPX 256              // pixels per k_gemm block window (R11 geometry)
#define SCH 32               // channels per staged chunk
#define NCHK 8               // 256 / SCH
#define PAD 4                // floats of row padding in LDS

typedef float f32x4 __attribute__((ext_vector_type(4)));
typedef float f32x2 __attribute__((ext_vector_type(2)));
typedef short bhalf8 __attribute__((ext_vector_type(8)));

// one instruction, two 4B LDS reads at vaddr+offset0*4 / vaddr+offset1*4
#define DSR2(dst, a, offs) asm volatile("ds_read2_b32 %0, %1 " offs : "=v"(dst) : "v"(a))

static __device__ __forceinline__ short f2bf(float f){
  __bf16 h = (__bf16)f;
  return __builtin_bit_cast(short, h);
}

// ws float layout: [256,320) probs[b][m] ; [320,2368) stats[(b*64+o)*2+{s,q}] ;
//                  [8192, +16*DBLK*10) block partials

__global__ void k_zero(float* ws){
  int i = blockIdx.x*256 + threadIdx.x;
  if (i < 2048) ws[320 + i] = 0.f;   // stats only
}

// Pass 1: Gram partials (proven ~50us / 5.4TB/s structure, untouched).
__global__ void k_dots(const float* __restrict__ x, float* __restrict__ partials){
  __shared__ float lds[4][WIN];
  __shared__ float red[4][16];
  const int b = blockIdx.y, bx = blockIdx.x;
  const int tid = threadIdx.x;
  const int w = tid >> 6, lane = tid & 63;
  const int wi = (bx + b*67) & (DBLK-1);
  const float* src = x + (size_t)b*4*NPM + (size_t)w*NPM + (size_t)wi*WIN + lane*4;

  #pragma unroll
  for (int li=0; li<4; li++){
    __builtin_amdgcn_global_load_lds(
        (const __attribute__((address_space(1))) void*)(src + li*256),
        (__attribute__((address_space(3))) void*)&lds[w][li*256],
        16, 0, 0);
  }
  __syncthreads();

  float4 vv[4];
  #pragma unroll
  for (int m=0;m<4;m++) vv[m] = *(const float4*)&lds[m][tid*4];
  float acc[10];
  int k=0;
  #pragma unroll
  for (int i=0;i<4;i++)
    #pragma unroll
    for (int j=i;j<4;j++,k++)
      acc[k] = vv[i].x*vv[j].x + vv[i].y*vv[j].y + vv[i].z*vv[j].z + vv[i].w*vv[j].w;

  #pragma unroll
  for (int kk=0;kk<10;kk++){
    float s = acc[kk];
    #pragma unroll
    for (int off=1; off<64; off<<=1) s += __shfl_xor(s, off, 64);
    acc[kk]=s;
  }
  if (lane==0){
    #pragma unroll
    for (int kk=0;kk<10;kk++) red[w][kk] = acc[kk];
  }
  __syncthreads();
  if (tid<10){
    float s = red[0][tid] + red[1][tid] + red[2][tid] + red[3][tid];
    partials[((size_t)b*DBLK + bx)*10 + tid] = s;
  }
}

__global__ void k_attn(const float* __restrict__ partials, float* __restrict__ probs){
  __shared__ float red[4][16];
  int b = blockIdx.x, tid = threadIdx.x;       // 256 threads
  int w = tid>>6, lane = tid&63;
  float a[10];
  #pragma unroll
  for (int kk=0;kk<10;kk++) a[kk]=0.f;
  #pragma unroll
  for (int r=0;r<DBLK/256;r++){
    const float* p = partials + ((size_t)b*DBLK + r*256 + tid)*10;
    #pragma unroll
    for (int kk=0;kk<10;kk++) a[kk]+=p[kk];
  }
  #pragma unroll
  for (int kk=0;kk<10;kk++){
    float s=a[kk];
    #pragma unroll
    for (int off=1;off<64;off<<=1) s+=__shfl_xor(s,off,64);
    a[kk]=s;
  }
  if (lane==0){
    #pragma unroll
    for (int kk=0;kk<10;kk++) red[w][kk]=a[kk];
  }
  __syncthreads();
  if (tid==0){
    float d[10];
    #pragma unroll
    for (int kk=0;kk<10;kk++) d[kk]=red[0][kk]+red[1][kk]+red[2][kk]+red[3][kk];
    float D[4][4];
    int k2=0;
    #pragma unroll
    for (int i=0;i<4;i++)
      #pragma unroll
      for (int j=i;j<4;j++,k2++){ D[i][j]=d[k2]; D[j][i]=d[k2]; }
    float nrm[4];
    #pragma unroll
    for (int m=0;m<4;m++) nrm[m]=fmaxf(sqrtf(D[m][m]),1e-8f);
    float sc[4];
    #pragma unroll
    for (int i=0;i<4;i++){
      float s=0.f;
      #pragma unroll
      for (int j=0;j<4;j++) s += D[i][j]/(nrm[i]*nrm[j]);
      sc[i] = -(s-1.0f);
    }
    float mx = fmaxf(fmaxf(sc[0],sc[1]), fmaxf(sc[2],sc[3]));
    float e[4], se=0.f;
    #pragma unroll
    for (int m=0;m<4;m++){ e[m]=expf(sc[m]-mx); se+=e[m]; }
    #pragma unroll
    for (int m=0;m<4;m++) probs[b*4+m]=e[m]/se;
  }
}

// GEMM: R11/R23 skeleton; compute phase re-done with ds_read2_b32 (pt-pairs
// merged: 64 -> 32 DS instructions per wave per chunk — the measured
// bottleneck is DS instruction issue, ~7cyc each, 110us total).
__launch_bounds__(256, 2)
__global__ void k_gemm(const float* __restrict__ x, const float* __restrict__ w,
                       const float* __restrict__ ws, float* __restrict__ y,
                       float* __restrict__ stats){
  __shared__ float buf[2][SCH][SPX+PAD];
  const int b   = blockIdx.y;
  const int pw  = blockIdx.x * SPX;
  const int tid = threadIdx.x;
  const int wid = tid >> 6;
  const int lane = tid & 63;
  const int l15 = lane & 15;
  const int lg  = lane >> 4;
  const int wr  = wid & 1;      // row half   (32 rows)
  const int wp  = wid >> 1;     // pixel half (128 px)

  const float* probs = ws + 256 + b*4;
  float pm[4] = {probs[0], probs[1], probs[2], probs[3]};
  bhalf8 afrag[2][NCHK];
  const float4* w4 = reinterpret_cast<const float4*>(w);
  #pragma unroll
  for (int rt=0; rt<2; rt++){
    int row = wr*32 + rt*16 + l15;
    #pragma unroll
    for (int ks=0; ks<NCHK; ks++){
      float s = pm[ks>>1];
      float4 a0 = w4[row*64 + ks*8 + lg];
      float4 a1 = w4[row*64 + ks*8 + lg + 4];
      bhalf8 f;
      f[0]=f2bf(a0.x*s); f[1]=f2bf(a0.y*s); f[2]=f2bf(a0.z*s); f[3]=f2bf(a0.w*s);
      f[4]=f2bf(a1.x*s); f[5]=f2bf(a1.y*s); f[6]=f2bf(a1.z*s); f[7]=f2bf(a1.w*s);
      afrag[rt][ks] = f;
    }
  }

  const float* xb = x + (size_t)b*NC*HW + pw;

  auto STAGE = [&](int cc, int cur){
    #pragma unroll
    for (int j=0; j<8; j++){
      int ch_l = wid*8 + j;
      __builtin_amdgcn_global_load_lds(
          (const __attribute__((address_space(1))) void*)(xb + (size_t)(cc*SCH + ch_l)*HW + lane*4),
          (__attribute__((address_space(3))) void*)&buf[cur][ch_l][0],
          16, 0, 0);
    }
  };

  f32x4 acc[2][8];
  #pragma unroll
  for (int rt=0; rt<2; rt++)
    #pragma unroll
    for (int pt=0; pt<8; pt++) acc[rt][pt] = (f32x4){0.f,0.f,0.f,0.f};

  const int px_base = wp*128 + l15;

  STAGE(0, 0);
  int cur = 0;
  #pragma unroll 1
  for (int cc=0; cc<NCHK; cc++){
    if (cc < NCHK-1){
      STAGE(cc+1, cur^1);
      asm volatile("s_waitcnt vmcnt(8)" ::: "memory");
    } else {
      asm volatile("s_waitcnt vmcnt(0)" ::: "memory");
    }
    __builtin_amdgcn_s_barrier();        // all waves' chunk-cc writes done
    __builtin_amdgcn_sched_barrier(0);

    // compute(cc): ds_read2_b32 pipeline over 4 pt-pairs.
    const uint32_t base = (uint32_t)(cur*SCH*(SPX+PAD)) * 4u;
    uint32_t ad[8];
    #pragma unroll
    for (int e=0; e<8; e++){
      int c_l = lg*4 + (e&3) + (e>>2)*16;
      ad[e] = base + (uint32_t)(c_l*(SPX+PAD) + px_base) * 4u;
    }
    f32x2 pA[8], pB[8];
    #pragma unroll
    for (int e=0; e<8; e++) DSR2(pA[e], ad[e], "offset0:0 offset1:16");

    #pragma unroll
    for (int pp=0; pp<4; pp++){
      if (pp == 0){
        #pragma unroll
        for (int e=0; e<8; e++) DSR2(pB[e], ad[e], "offset0:32 offset1:48");
        asm volatile("s_waitcnt lgkmcnt(8)" ::: "memory");
      } else if (pp == 1){
        #pragma unroll
        for (int e=0; e<8; e++) DSR2(pA[e], ad[e], "offset0:64 offset1:80");
        asm volatile("s_waitcnt lgkmcnt(8)" ::: "memory");
      } else if (pp == 2){
        #pragma unroll
        for (int e=0; e<8; e++) DSR2(pB[e], ad[e], "offset0:96 offset1:112");
        asm volatile("s_waitcnt lgkmcnt(8)" ::: "memory");
      } else {
        asm volatile("s_waitcnt lgkmcnt(0)" ::: "memory");
      }
      __builtin_amdgcn_sched_barrier(0);   // rule #18: no consumer hoisting

      const f32x2* cp = (pp&1) ? pB : pA;  // pair issued before this pp's prefetch
      bhalf8 b0, b1;
      #pragma unroll
      for (int e=0; e<8; e++){ b0[e] = f2bf(cp[e].x); b1[e] = f2bf(cp[e].y); }
      #pragma unroll
      for (int rt=0; rt<2; rt++){
        acc[rt][2*pp]   = __builtin_amdgcn_mfma_f32_16x16x32_bf16(afrag[rt][cc], b0, acc[rt][2*pp],   0, 0, 0);
        acc[rt][2*pp+1] = __builtin_amdgcn_mfma_f32_16x16x32_bf16(afrag[rt][cc], b1, acc[rt][2*pp+1], 0, 0, 0);
      }
    }

    __builtin_amdgcn_sched_barrier(0);
    __builtin_amdgcn_s_barrier();        // reads done -> buf[cur] reusable
    cur ^= 1;
  }

  // epilogue: y write + stats (C/D: row = lg*4 + r, col = l15)
  float sacc[2][4] = {{0}}, qacc[2][4] = {{0}};
  #pragma unroll
  for (int rt=0; rt<2; rt++){
    #pragma unroll
    for (int pt=0; pt<8; pt++){
      size_t ybase = ((size_t)(b*NO + wr*32 + rt*16 + lg*4))*HW + pw + wp*128 + pt*16 + l15;
      #pragma unroll
      for (int r=0; r<4; r++){
        float v = acc[rt][pt][r];
        y[ybase + (size_t)r*HW] = v;
        sacc[rt][r] += v;
        qacc[rt][r] += v*v;
      }
    }
  }
  #pragma unroll
  for (int rt=0; rt<2; rt++){
    #pragma unroll
    for (int r=0; r<4; r++){
      float s = sacc[rt][r], q = qacc[rt][r];
      #pragma unroll
      for (int off=1; off<16; off<<=1){
        s += __shfl_xor(s, off, 64);
        q += __shfl_xor(q, off, 64);
      }
      if (l15 == 0){
        int o = wr*32 + rt*16 + lg*4 + r;
        atomicAdd(&stats[b*128 + o*2],     s);
        atomicAdd(&stats[b*128 + o*2 + 1], q);
      }
    }
  }
}

__global__ void k_norm(float* __restrict__ y, const float* __restrict__ stats){
  int bo = blockIdx.x;
  float s = stats[bo*2], q = stats[bo*2+1];
  float mean = s * (1.f/HW);
  float var  = q * (1.f/HW) - mean*mean;
  float inv  = rsqrtf(var + EPS_IN);
  float4* yp = reinterpret_cast<float4*>(y) + (size_t)bo*(HW/4);
  #pragma unroll 4
  for (int i = threadIdx.x; i < HW/4; i += 256){
    float4 v = yp[i];
    v.x = fmaxf((v.x-mean)*inv, 0.f);
    v.y = fmaxf((v.y-mean)*inv, 0.f);
    v.z = fmaxf((v.z-mean)*inv, 0.f);
    v.w = fmaxf((v.w-mean)*inv, 0.f);
    yp[i] = v;
  }
}

extern "C" void kernel_launch(void* const* d_in, const int* in_sizes, int n_in,
                              void* d_out, int out_size, void* d_ws, size_t ws_size,
                              hipStream_t stream){
  const float* x = (const float*)d_in[0];
  const float* w = (const float*)d_in[1];
  float* out = (float*)d_out;
  float* ws  = (float*)d_ws;
  float* partials = ws + 8192;
  float* probs    = ws + 256;
  float* stats    = ws + 320;

  k_zero<<<dim3(8),          dim3(256), 0, stream>>>(ws);
  k_dots<<<dim3(DBLK,16),    dim3(256), 0, stream>>>(x, partials);
  k_attn<<<dim3(16),         dim3(256), 0, stream>>>(partials, probs);
  k_gemm<<<dim3(HW/SPX,16),  dim3(256), 0, stream>>>(x, w, ws, out, stats);
  k_norm<<<dim3(1024),       dim3(256), 0, stream>>>(out, stats);
}

// Round 26
// 211.297 us; speedup vs baseline: 1.2506x; 1.0106x over previous
//
#include <hip/hip_runtime.h>
#include <hip/hip_bf16.h>

#define HW 16384
#define NC 256
#define NO 64
#define NPM 1048576          // floats per (b, modality)
#define EPS_IN 1e-5f
#define DBLK 1024            // k_dots blocks.x
#define WIN 1024             // floats per modality per window
#define SPX 256              // pixels per k_gemm block window (R11 geometry)
#define SCH 32               // channels per staged chunk
#define NCHK 8               // 256 / SCH
#define PAD 4                // floats of row padding in LDS

typedef float f32x4 __attribute__((ext_vector_type(4)));
typedef short bhalf8 __attribute__((ext_vector_type(8)));

static __device__ __forceinline__ short f2bf(float f){
  __bf16 h = (__bf16)f;
  return __builtin_bit_cast(short, h);
}

// ws float layout: [256,320) probs[b][m] ; [320,2368) stats[(b*64+o)*2+{s,q}] ;
//                  [8192, +16*DBLK*10) block partials

__global__ void k_zero(float* ws){
  int i = blockIdx.x*256 + threadIdx.x;
  if (i < 2048) ws[320 + i] = 0.f;   // stats only
}

// Pass 1: Gram partials (proven ~50us / 5.4TB/s structure, untouched).
__global__ void k_dots(const float* __restrict__ x, float* __restrict__ partials){
  __shared__ float lds[4][WIN];
  __shared__ float red[4][16];
  const int b = blockIdx.y, bx = blockIdx.x;
  const int tid = threadIdx.x;
  const int w = tid >> 6, lane = tid & 63;
  const int wi = (bx + b*67) & (DBLK-1);
  const float* src = x + (size_t)b*4*NPM + (size_t)w*NPM + (size_t)wi*WIN + lane*4;

  #pragma unroll
  for (int li=0; li<4; li++){
    __builtin_amdgcn_global_load_lds(
        (const __attribute__((address_space(1))) void*)(src + li*256),
        (__attribute__((address_space(3))) void*)&lds[w][li*256],
        16, 0, 0);
  }
  __syncthreads();

  float4 vv[4];
  #pragma unroll
  for (int m=0;m<4;m++) vv[m] = *(const float4*)&lds[m][tid*4];
  float acc[10];
  int k=0;
  #pragma unroll
  for (int i=0;i<4;i++)
    #pragma unroll
    for (int j=i;j<4;j++,k++)
      acc[k] = vv[i].x*vv[j].x + vv[i].y*vv[j].y + vv[i].z*vv[j].z + vv[i].w*vv[j].w;

  #pragma unroll
  for (int kk=0;kk<10;kk++){
    float s = acc[kk];
    #pragma unroll
    for (int off=1; off<64; off<<=1) s += __shfl_xor(s, off, 64);
    acc[kk]=s;
  }
  if (lane==0){
    #pragma unroll
    for (int kk=0;kk<10;kk++) red[w][kk] = acc[kk];
  }
  __syncthreads();
  if (tid<10){
    float s = red[0][tid] + red[1][tid] + red[2][tid] + red[3][tid];
    partials[((size_t)b*DBLK + bx)*10 + tid] = s;
  }
}

__global__ void k_attn(const float* __restrict__ partials, float* __restrict__ probs){
  __shared__ float red[4][16];
  int b = blockIdx.x, tid = threadIdx.x;       // 256 threads
  int w = tid>>6, lane = tid&63;
  float a[10];
  #pragma unroll
  for (int kk=0;kk<10;kk++) a[kk]=0.f;
  #pragma unroll
  for (int r=0;r<DBLK/256;r++){
    const float* p = partials + ((size_t)b*DBLK + r*256 + tid)*10;
    #pragma unroll
    for (int kk=0;kk<10;kk++) a[kk]+=p[kk];
  }
  #pragma unroll
  for (int kk=0;kk<10;kk++){
    float s=a[kk];
    #pragma unroll
    for (int off=1;off<64;off<<=1) s+=__shfl_xor(s,off,64);
    a[kk]=s;
  }
  if (lane==0){
    #pragma unroll
    for (int kk=0;kk<10;kk++) red[w][kk]=a[kk];
  }
  __syncthreads();
  if (tid==0){
    float d[10];
    #pragma unroll
    for (int kk=0;kk<10;kk++) d[kk]=red[0][kk]+red[1][kk]+red[2][kk]+red[3][kk];
    float D[4][4];
    int k2=0;
    #pragma unroll
    for (int i=0;i<4;i++)
      #pragma unroll
      for (int j=i;j<4;j++,k2++){ D[i][j]=d[k2]; D[j][i]=d[k2]; }
    float nrm[4];
    #pragma unroll
    for (int m=0;m<4;m++) nrm[m]=fmaxf(sqrtf(D[m][m]),1e-8f);
    float sc[4];
    #pragma unroll
    for (int i=0;i<4;i++){
      float s=0.f;
      #pragma unroll
      for (int j=0;j<4;j++) s += D[i][j]/(nrm[i]*nrm[j]);
      sc[i] = -(s-1.0f);
    }
    float mx = fmaxf(fmaxf(sc[0],sc[1]), fmaxf(sc[2],sc[3]));
    float e[4], se=0.f;
    #pragma unroll
    for (int m=0;m<4;m++){ e[m]=expf(sc[m]-mx); se+=e[m]; }
    #pragma unroll
    for (int m=0;m<4;m++) probs[b*4+m]=e[m]/se;
  }
}

// GEMM: R11's proven kernel + NON-TEMPORAL y stores (nt bypasses L2
// allocation -> x-read stream keeps the cache path; DRAM sees longer
// same-direction bursts). Counted-vmcnt dbuf skeleton unchanged.
__launch_bounds__(256, 2)
__global__ void k_gemm(const float* __restrict__ x, const float* __restrict__ w,
                       const float* __restrict__ ws, float* __restrict__ y,
                       float* __restrict__ stats){
  __shared__ float buf[2][SCH][SPX+PAD];
  const int b   = blockIdx.y;
  const int pw  = blockIdx.x * SPX;
  const int tid = threadIdx.x;
  const int wid = tid >> 6;
  const int lane = tid & 63;
  const int l15 = lane & 15;
  const int lg  = lane >> 4;
  const int wr  = wid & 1;      // row half   (32 rows)
  const int wp  = wid >> 1;     // pixel half (128 px)

  const float* probs = ws + 256 + b*4;
  float pm[4] = {probs[0], probs[1], probs[2], probs[3]};
  bhalf8 afrag[2][NCHK];
  const float4* w4 = reinterpret_cast<const float4*>(w);
  #pragma unroll
  for (int rt=0; rt<2; rt++){
    int row = wr*32 + rt*16 + l15;
    #pragma unroll
    for (int ks=0; ks<NCHK; ks++){
      float s = pm[ks>>1];
      float4 a0 = w4[row*64 + ks*8 + lg];
      float4 a1 = w4[row*64 + ks*8 + lg + 4];
      bhalf8 f;
      f[0]=f2bf(a0.x*s); f[1]=f2bf(a0.y*s); f[2]=f2bf(a0.z*s); f[3]=f2bf(a0.w*s);
      f[4]=f2bf(a1.x*s); f[5]=f2bf(a1.y*s); f[6]=f2bf(a1.z*s); f[7]=f2bf(a1.w*s);
      afrag[rt][ks] = f;
    }
  }

  const float* xb = x + (size_t)b*NC*HW + pw;

  auto STAGE = [&](int cc, int cur){
    #pragma unroll
    for (int j=0; j<8; j++){
      int ch_l = wid*8 + j;
      __builtin_amdgcn_global_load_lds(
          (const __attribute__((address_space(1))) void*)(xb + (size_t)(cc*SCH + ch_l)*HW + lane*4),
          (__attribute__((address_space(3))) void*)&buf[cur][ch_l][0],
          16, 0, 0);
    }
  };

  f32x4 acc[2][8];
  #pragma unroll
  for (int rt=0; rt<2; rt++)
    #pragma unroll
    for (int pt=0; pt<8; pt++) acc[rt][pt] = (f32x4){0.f,0.f,0.f,0.f};

  STAGE(0, 0);
  int cur = 0;
  #pragma unroll 1
  for (int cc=0; cc<NCHK; cc++){
    if (cc < NCHK-1){
      STAGE(cc+1, cur^1);
      asm volatile("s_waitcnt vmcnt(8)" ::: "memory");
    } else {
      asm volatile("s_waitcnt vmcnt(0)" ::: "memory");
    }
    __builtin_amdgcn_s_barrier();        // all waves' chunk-cc writes done
    __builtin_amdgcn_sched_barrier(0);

    const float (*bp)[SPX+PAD] = buf[cur];
    #pragma unroll
    for (int pt=0; pt<8; pt++){
      int px_l = wp*128 + pt*16 + l15;
      bhalf8 bfr;
      #pragma unroll
      for (int eh=0; eh<2; eh++)
        #pragma unroll
        for (int el=0; el<4; el++){
          int c_l = lg*4 + el + eh*16;
          bfr[eh*4+el] = f2bf(bp[c_l][px_l]);
        }
      #pragma unroll
      for (int rt=0; rt<2; rt++)
        acc[rt][pt] = __builtin_amdgcn_mfma_f32_16x16x32_bf16(afrag[rt][cc], bfr, acc[rt][pt], 0, 0, 0);
    }

    __builtin_amdgcn_sched_barrier(0);
    __builtin_amdgcn_s_barrier();        // reads done -> buf[cur] reusable
    cur ^= 1;
  }

  // epilogue: NT y write + stats (C/D: row = lg*4 + r, col = l15)
  float sacc[2][4] = {{0}}, qacc[2][4] = {{0}};
  #pragma unroll
  for (int rt=0; rt<2; rt++){
    #pragma unroll
    for (int pt=0; pt<8; pt++){
      size_t ybase = ((size_t)(b*NO + wr*32 + rt*16 + lg*4))*HW + pw + wp*128 + pt*16 + l15;
      #pragma unroll
      for (int r=0; r<4; r++){
        float v = acc[rt][pt][r];
        __builtin_nontemporal_store(v, &y[ybase + (size_t)r*HW]);
        sacc[rt][r] += v;
        qacc[rt][r] += v*v;
      }
    }
  }
  #pragma unroll
  for (int rt=0; rt<2; rt++){
    #pragma unroll
    for (int r=0; r<4; r++){
      float s = sacc[rt][r], q = qacc[rt][r];
      #pragma unroll
      for (int off=1; off<16; off<<=1){
        s += __shfl_xor(s, off, 64);
        q += __shfl_xor(q, off, 64);
      }
      if (l15 == 0){
        int o = wr*32 + rt*16 + lg*4 + r;
        atomicAdd(&stats[b*128 + o*2],     s);
        atomicAdd(&stats[b*128 + o*2 + 1], q);
      }
    }
  }
}

__global__ void k_norm(float* __restrict__ y, const float* __restrict__ stats){
  int bo = blockIdx.x;
  float s = stats[bo*2], q = stats[bo*2+1];
  float mean = s * (1.f/HW);
  float var  = q * (1.f/HW) - mean*mean;
  float inv  = rsqrtf(var + EPS_IN);
  f32x4* yp = reinterpret_cast<f32x4*>(y) + (size_t)bo*(HW/4);
  #pragma unroll 4
  for (int i = threadIdx.x; i < HW/4; i += 256){
    f32x4 v = yp[i];
    v.x = fmaxf((v.x-mean)*inv, 0.f);
    v.y = fmaxf((v.y-mean)*inv, 0.f);
    v.z = fmaxf((v.z-mean)*inv, 0.f);
    v.w = fmaxf((v.w-mean)*inv, 0.f);
    __builtin_nontemporal_store(v, &yp[i]);
  }
}

extern "C" void kernel_launch(void* const* d_in, const int* in_sizes, int n_in,
                              void* d_out, int out_size, void* d_ws, size_t ws_size,
                              hipStream_t stream){
  const float* x = (const float*)d_in[0];
  const float* w = (const float*)d_in[1];
  float* out = (float*)d_out;
  float* ws  = (float*)d_ws;
  float* partials = ws + 8192;
  float* probs    = ws + 256;
  float* stats    = ws + 320;

  k_zero<<<dim3(8),          dim3(256), 0, stream>>>(ws);
  k_dots<<<dim3(DBLK,16),    dim3(256), 0, stream>>>(x, partials);
  k_attn<<<dim3(16),         dim3(256), 0, stream>>>(partials, probs);
  k_gemm<<<dim3(HW/SPX,16),  dim3(256), 0, stream>>>(x, w, ws, out, stats);
  k_norm<<<dim3(1024),       dim3(256), 0, stream>>>(out, stats);
}

// Round 27
// 172.552 us; speedup vs baseline: 1.5314x; 1.2245x over previous
//
#include <hip/hip_runtime.h>
#include <hip/hip_bf16.h>

#define HW 16384
#define NC 256
#define NO 64
#define NPM 1048576          // floats per (b, modality)
#define EPS_IN 1e-5f
#define DBLK 1024            // k_dots blocks.x
#define WIN 1024             // floats per modality per window
#define SPX 256              // pixels per k_gemm block window (R11 geometry)
#define SCH 32               // channels per staged chunk
#define NCHK 8               // 256 / SCH
#define PAD 4                // floats of row padding in LDS

typedef float f32x4 __attribute__((ext_vector_type(4)));
typedef short bhalf8 __attribute__((ext_vector_type(8)));

static __device__ __forceinline__ short f2bf(float f){
  __bf16 h = (__bf16)f;
  return __builtin_bit_cast(short, h);
}

// ws float layout: [256,320) probs[b][m] ; [8192, 8192+163840) dots partials ;
//                  [180224, 180224+262144) gemm stats partials part[b][bx][o][4]
//                  (all fully overwritten every call -> no zeroing needed)

// Pass 1: Gram partials (proven ~50us / 5.4TB/s structure, untouched).
__global__ void k_dots(const float* __restrict__ x, float* __restrict__ partials){
  __shared__ float lds[4][WIN];
  __shared__ float red[4][16];
  const int b = blockIdx.y, bx = blockIdx.x;
  const int tid = threadIdx.x;
  const int w = tid >> 6, lane = tid & 63;
  const int wi = (bx + b*67) & (DBLK-1);
  const float* src = x + (size_t)b*4*NPM + (size_t)w*NPM + (size_t)wi*WIN + lane*4;

  #pragma unroll
  for (int li=0; li<4; li++){
    __builtin_amdgcn_global_load_lds(
        (const __attribute__((address_space(1))) void*)(src + li*256),
        (__attribute__((address_space(3))) void*)&lds[w][li*256],
        16, 0, 0);
  }
  __syncthreads();

  float4 vv[4];
  #pragma unroll
  for (int m=0;m<4;m++) vv[m] = *(const float4*)&lds[m][tid*4];
  float acc[10];
  int k=0;
  #pragma unroll
  for (int i=0;i<4;i++)
    #pragma unroll
    for (int j=i;j<4;j++,k++)
      acc[k] = vv[i].x*vv[j].x + vv[i].y*vv[j].y + vv[i].z*vv[j].z + vv[i].w*vv[j].w;

  #pragma unroll
  for (int kk=0;kk<10;kk++){
    float s = acc[kk];
    #pragma unroll
    for (int off=1; off<64; off<<=1) s += __shfl_xor(s, off, 64);
    acc[kk]=s;
  }
  if (lane==0){
    #pragma unroll
    for (int kk=0;kk<10;kk++) red[w][kk] = acc[kk];
  }
  __syncthreads();
  if (tid<10){
    float s = red[0][tid] + red[1][tid] + red[2][tid] + red[3][tid];
    partials[((size_t)b*DBLK + bx)*10 + tid] = s;
  }
}

__global__ void k_attn(const float* __restrict__ partials, float* __restrict__ probs){
  __shared__ float red[4][16];
  int b = blockIdx.x, tid = threadIdx.x;       // 256 threads
  int w = tid>>6, lane = tid&63;
  float a[10];
  #pragma unroll
  for (int kk=0;kk<10;kk++) a[kk]=0.f;
  #pragma unroll
  for (int r=0;r<DBLK/256;r++){
    const float* p = partials + ((size_t)b*DBLK + r*256 + tid)*10;
    #pragma unroll
    for (int kk=0;kk<10;kk++) a[kk]+=p[kk];
  }
  #pragma unroll
  for (int kk=0;kk<10;kk++){
    float s=a[kk];
    #pragma unroll
    for (int off=1;off<64;off<<=1) s+=__shfl_xor(s,off,64);
    a[kk]=s;
  }
  if (lane==0){
    #pragma unroll
    for (int kk=0;kk<10;kk++) red[w][kk]=a[kk];
  }
  __syncthreads();
  if (tid==0){
    float d[10];
    #pragma unroll
    for (int kk=0;kk<10;kk++) d[kk]=red[0][kk]+red[1][kk]+red[2][kk]+red[3][kk];
    float D[4][4];
    int k2=0;
    #pragma unroll
    for (int i=0;i<4;i++)
      #pragma unroll
      for (int j=i;j<4;j++,k2++){ D[i][j]=d[k2]; D[j][i]=d[k2]; }
    float nrm[4];
    #pragma unroll
    for (int m=0;m<4;m++) nrm[m]=fmaxf(sqrtf(D[m][m]),1e-8f);
    float sc[4];
    #pragma unroll
    for (int i=0;i<4;i++){
      float s=0.f;
      #pragma unroll
      for (int j=0;j<4;j++) s += D[i][j]/(nrm[i]*nrm[j]);
      sc[i] = -(s-1.0f);
    }
    float mx = fmaxf(fmaxf(sc[0],sc[1]), fmaxf(sc[2],sc[3]));
    float e[4], se=0.f;
    #pragma unroll
    for (int m=0;m<4;m++){ e[m]=expf(sc[m]-mx); se+=e[m]; }
    #pragma unroll
    for (int m=0;m<4;m++) probs[b*4+m]=e[m]/se;
  }
}

// GEMM: R26 kernel with ZERO global atomics — per-block stats plain-stored to
// a private slot; k_norm pre-reduces. (Atomics are the only component present
// in the real kernel but absent from both fast R22 probes.)
__launch_bounds__(256, 2)
__global__ void k_gemm(const float* __restrict__ x, const float* __restrict__ w,
                       const float* __restrict__ ws, float* __restrict__ y,
                       float* __restrict__ part){
  __shared__ float buf[2][SCH][SPX+PAD];
  const int b   = blockIdx.y;
  const int pw  = blockIdx.x * SPX;
  const int tid = threadIdx.x;
  const int wid = tid >> 6;
  const int lane = tid & 63;
  const int l15 = lane & 15;
  const int lg  = lane >> 4;
  const int wr  = wid & 1;      // row half   (32 rows)
  const int wp  = wid >> 1;     // pixel half (128 px)

  const float* probs = ws + 256 + b*4;
  float pm[4] = {probs[0], probs[1], probs[2], probs[3]};
  bhalf8 afrag[2][NCHK];
  const float4* w4 = reinterpret_cast<const float4*>(w);
  #pragma unroll
  for (int rt=0; rt<2; rt++){
    int row = wr*32 + rt*16 + l15;
    #pragma unroll
    for (int ks=0; ks<NCHK; ks++){
      float s = pm[ks>>1];
      float4 a0 = w4[row*64 + ks*8 + lg];
      float4 a1 = w4[row*64 + ks*8 + lg + 4];
      bhalf8 f;
      f[0]=f2bf(a0.x*s); f[1]=f2bf(a0.y*s); f[2]=f2bf(a0.z*s); f[3]=f2bf(a0.w*s);
      f[4]=f2bf(a1.x*s); f[5]=f2bf(a1.y*s); f[6]=f2bf(a1.z*s); f[7]=f2bf(a1.w*s);
      afrag[rt][ks] = f;
    }
  }

  const float* xb = x + (size_t)b*NC*HW + pw;

  auto STAGE = [&](int cc, int cur){
    #pragma unroll
    for (int j=0; j<8; j++){
      int ch_l = wid*8 + j;
      __builtin_amdgcn_global_load_lds(
          (const __attribute__((address_space(1))) void*)(xb + (size_t)(cc*SCH + ch_l)*HW + lane*4),
          (__attribute__((address_space(3))) void*)&buf[cur][ch_l][0],
          16, 0, 0);
    }
  };

  f32x4 acc[2][8];
  #pragma unroll
  for (int rt=0; rt<2; rt++)
    #pragma unroll
    for (int pt=0; pt<8; pt++) acc[rt][pt] = (f32x4){0.f,0.f,0.f,0.f};

  STAGE(0, 0);
  int cur = 0;
  #pragma unroll 1
  for (int cc=0; cc<NCHK; cc++){
    if (cc < NCHK-1){
      STAGE(cc+1, cur^1);
      asm volatile("s_waitcnt vmcnt(8)" ::: "memory");
    } else {
      asm volatile("s_waitcnt vmcnt(0)" ::: "memory");
    }
    __builtin_amdgcn_s_barrier();        // all waves' chunk-cc writes done
    __builtin_amdgcn_sched_barrier(0);

    const float (*bp)[SPX+PAD] = buf[cur];
    #pragma unroll
    for (int pt=0; pt<8; pt++){
      int px_l = wp*128 + pt*16 + l15;
      bhalf8 bfr;
      #pragma unroll
      for (int eh=0; eh<2; eh++)
        #pragma unroll
        for (int el=0; el<4; el++){
          int c_l = lg*4 + el + eh*16;
          bfr[eh*4+el] = f2bf(bp[c_l][px_l]);
        }
      #pragma unroll
      for (int rt=0; rt<2; rt++)
        acc[rt][pt] = __builtin_amdgcn_mfma_f32_16x16x32_bf16(afrag[rt][cc], bfr, acc[rt][pt], 0, 0, 0);
    }

    __builtin_amdgcn_sched_barrier(0);
    __builtin_amdgcn_s_barrier();        // reads done -> buf[cur] reusable
    cur ^= 1;
  }

  // epilogue: NT y write + per-block stats stores (NO atomics)
  float sacc[2][4] = {{0}}, qacc[2][4] = {{0}};
  #pragma unroll
  for (int rt=0; rt<2; rt++){
    #pragma unroll
    for (int pt=0; pt<8; pt++){
      size_t ybase = ((size_t)(b*NO + wr*32 + rt*16 + lg*4))*HW + pw + wp*128 + pt*16 + l15;
      #pragma unroll
      for (int r=0; r<4; r++){
        float v = acc[rt][pt][r];
        __builtin_nontemporal_store(v, &y[ybase + (size_t)r*HW]);
        sacc[rt][r] += v;
        qacc[rt][r] += v*v;
      }
    }
  }
  float* sp = part + ((size_t)(b*64 + blockIdx.x))*NO*4;   // [o][4]: s,q per wp
  #pragma unroll
  for (int rt=0; rt<2; rt++){
    #pragma unroll
    for (int r=0; r<4; r++){
      float s = sacc[rt][r], q = qacc[rt][r];
      #pragma unroll
      for (int off=1; off<16; off<<=1){
        s += __shfl_xor(s, off, 64);
        q += __shfl_xor(q, off, 64);
      }
      if (l15 == 0){
        int o = wr*32 + rt*16 + lg*4 + r;
        sp[o*4 + wp*2]     = s;
        sp[o*4 + wp*2 + 1] = q;
      }
    }
  }
}

__global__ void k_norm(float* __restrict__ y, const float* __restrict__ part){
  __shared__ float red2[2][2];
  const int bo = blockIdx.x, b = bo >> 6, o = bo & 63;
  const int tid = threadIdx.x;
  float s = 0.f, q = 0.f;
  if (tid < 128){
    int bx = tid >> 1, wp = tid & 1;
    const float* p = part + (((size_t)(b*64 + bx))*NO + o)*4 + wp*2;
    s = p[0]; q = p[1];
  }
  #pragma unroll
  for (int off=1; off<64; off<<=1){
    s += __shfl_xor(s, off, 64);
    q += __shfl_xor(q, off, 64);
  }
  if (tid < 128 && (tid & 63) == 0){ red2[tid>>6][0] = s; red2[tid>>6][1] = q; }
  __syncthreads();
  float S = red2[0][0] + red2[1][0];
  float Q = red2[0][1] + red2[1][1];
  float mean = S * (1.f/HW);
  float var  = Q * (1.f/HW) - mean*mean;
  float inv  = rsqrtf(var + EPS_IN);
  f32x4* yp = reinterpret_cast<f32x4*>(y) + (size_t)bo*(HW/4);
  #pragma unroll 4
  for (int i = tid; i < HW/4; i += 256){
    f32x4 v = yp[i];
    v.x = fmaxf((v.x-mean)*inv, 0.f);
    v.y = fmaxf((v.y-mean)*inv, 0.f);
    v.z = fmaxf((v.z-mean)*inv, 0.f);
    v.w = fmaxf((v.w-mean)*inv, 0.f);
    __builtin_nontemporal_store(v, &yp[i]);
  }
}

extern "C" void kernel_launch(void* const* d_in, const int* in_sizes, int n_in,
                              void* d_out, int out_size, void* d_ws, size_t ws_size,
                              hipStream_t stream){
  const float* x = (const float*)d_in[0];
  const float* w = (const float*)d_in[1];
  float* out = (float*)d_out;
  float* ws  = (float*)d_ws;
  float* partials = ws + 8192;
  float* probs    = ws + 256;
  float* part     = ws + 180224;

  k_dots<<<dim3(DBLK,16),    dim3(256), 0, stream>>>(x, partials);
  k_attn<<<dim3(16),         dim3(256), 0, stream>>>(partials, probs);
  k_gemm<<<dim3(HW/SPX,16),  dim3(256), 0, stream>>>(x, w, ws, out, part);
  k_norm<<<dim3(1024),       dim3(256), 0, stream>>>(out, part);
}